// Round 8
// baseline (377.301 us; speedup 1.0000x reference)
//
#include <hip/hip_runtime.h>
#include <hip/hip_bf16.h>
#include <math.h>

#define N_NODES 50000
#define N_EDGES 500000
#define C_DIM 128
#define N_TILES 3125   // 50000/16 exact

#define CSR_BLOCKS 1954      // ceil(500000/256)
#define CONCAT_BLOCKS 3125   // 50000*16/256
#define PACK_BLOCKS 480      // (20*8*512 + 20*4*512)/256

typedef __attribute__((ext_vector_type(8))) short bf8;
typedef __attribute__((ext_vector_type(4))) float f32x4;

__device__ __forceinline__ float bflo(unsigned u) { return __uint_as_float(u << 16); }
__device__ __forceinline__ float bfhi(unsigned u) { return __uint_as_float(u & 0xffff0000u); }
__device__ __forceinline__ unsigned short f2bfu(float f) {
    __hip_bfloat16 h = __float2bfloat16(f);
    unsigned short u;
    __builtin_memcpy(&u, &h, 2);
    return u;
}
__device__ __forceinline__ unsigned packbf(float a, float b) {
    return ((unsigned)f2bfu(b) << 16) | f2bfu(a);
}

// ---------------- graph preprocessing ----------------

__global__ void count_deg(const int* __restrict__ row, const int* __restrict__ col,
                          int* __restrict__ dout, int* __restrict__ din, int e) {
    int i = blockIdx.x * blockDim.x + threadIdx.x;
    if (i >= e) return;
    atomicAdd(&dout[row[i]], 1);
    atomicAdd(&din[col[i]], 1);
}

__global__ void scan_block(const int* __restrict__ counts, int* __restrict__ excl,
                           int* __restrict__ blocksums, int n) {
    __shared__ int tmp[1024];
    int tid = threadIdx.x;
    int gid = blockIdx.x * 1024 + tid;
    int v = (gid < n) ? counts[gid] : 0;
    tmp[tid] = v;
    __syncthreads();
    for (int off = 1; off < 1024; off <<= 1) {
        int t = (tid >= off) ? tmp[tid - off] : 0;
        __syncthreads();
        tmp[tid] += t;
        __syncthreads();
    }
    int incl = tmp[tid];
    if (gid < n) excl[gid] = incl - v;
    if (tid == 1023) blocksums[blockIdx.x] = incl;
}

__global__ void scan_sums(int* __restrict__ blocksums, int nb) {
    __shared__ int tmp[64];
    int tid = threadIdx.x;
    int v = (tid < nb) ? blocksums[tid] : 0;
    tmp[tid] = v;
    __syncthreads();
    for (int off = 1; off < 64; off <<= 1) {
        int t = (tid >= off) ? tmp[tid - off] : 0;
        __syncthreads();
        tmp[tid] += t;
        __syncthreads();
    }
    if (tid < nb) blocksums[tid] = tmp[tid] - v;
}

__global__ void scan_add(int* __restrict__ rowptr, const int* __restrict__ blocksums,
                         int* __restrict__ cursor, const int* __restrict__ dout,
                         const int* __restrict__ din, float2* __restrict__ winv,
                         int n, int e_total) {
    int gid = blockIdx.x * blockDim.x + threadIdx.x;
    if (gid < n) {
        int v = rowptr[gid] + blocksums[gid >> 10];
        rowptr[gid] = v;
        cursor[gid] = v;
        winv[gid] = make_float2(1.0f / (float)dout[gid], 1.0f / (float)din[gid]);
    }
    if (gid == n) rowptr[n] = e_total;
}

// ---------------- weight helpers ----------------
__device__ __forceinline__ float wraw(const float* W, int d, int kk, int k, int j) {
    return W[((d * 3 + kk) * 128 + k) * 64 + j];
}

__device__ __forceinline__ float zr_val(const float* Wz, const float* Wr, int k, int nn) {
    const float* W = (nn < 64) ? Wz : Wr;
    int j = nn & 63;
    if (k < 128) return wraw(W, 0, 0, k, j) + wraw(W, 1, 0, k, j);
    int k2 = k - 128;
    int kk = (k2 >= 256) ? 2 : 1;
    int k3 = k2 & 255;
    int p = k3 >> 2, sub = k3 & 3;
    return wraw(W, sub >> 1, kk, 2 * p + (sub & 1), j);
}

__device__ __forceinline__ float h_val(const float* Wh, int k, int j) {
    if (k < 64) return wraw(Wh, 0, 0, k, j) + wraw(Wh, 1, 0, k, j);
    if (k < 320) {
        int k2 = k - 64;
        int kk = (k2 >= 128) ? 2 : 1;
        int k3 = k2 & 127;
        int p = k3 >> 2, sub = k3 & 3;
        return wraw(Wh, sub >> 1, kk, 2 * p + (sub & 1), j);
    }
    if (k < 384) return wraw(Wh, 0, 0, 64 + (k - 320), j) + wraw(Wh, 1, 0, 64 + (k - 320), j);
    int k2 = k - 384;
    int kk = (k2 >= 128) ? 2 : 1;
    int k3 = k2 & 127;
    int p = k3 >> 2, sub = k3 & 3;
    return wraw(Wh, sub >> 1, kk, 64 + 2 * p + (sub & 1), j);
}

// ---------------- fused prep: build_csr + concat_xh + pack_weights ----------
__global__ void fused_prep(const int* __restrict__ row, const int* __restrict__ col,
                           const float2* __restrict__ winv, int* __restrict__ cursor,
                           int* __restrict__ csr_src, float2* __restrict__ csr_w,
                           const float* __restrict__ X, const float* __restrict__ Hm,
                           unsigned short* __restrict__ XH, unsigned short* __restrict__ XHp,
                           const float* __restrict__ Wz, const float* __restrict__ Wr,
                           const float* __restrict__ Wh,
                           unsigned short* __restrict__ Wzrf, unsigned short* __restrict__ Whf,
                           int n, int e) {
    int b = blockIdx.x;
    if (b < CSR_BLOCKS) {
        int i = b * 256 + threadIdx.x;
        if (i >= e) return;
        int r = row[i], c = col[i];
        int pos = atomicAdd(&cursor[c], 1);
        csr_src[pos] = r;
        csr_w[pos] = winv[r];
    } else if (b < CSR_BLOCKS + CONCAT_BLOCKS) {
        int t = (b - CSR_BLOCKS) * 256 + threadIdx.x;   // < n*16 exactly
        int node = t >> 4, p = t & 15;
        const float* src = (p < 8) ? (X + (size_t)node * 64 + 8 * p)
                                   : (Hm + (size_t)node * 64 + 8 * (p - 8));
        float4 v0 = *(const float4*)src;
        float4 v1 = *(const float4*)(src + 4);
        uint4 o;
        o.x = packbf(v0.x, v0.y); o.y = packbf(v0.z, v0.w);
        o.z = packbf(v1.x, v1.y); o.w = packbf(v1.z, v1.w);
        *(uint4*)(XH + (size_t)node * 128 + 8 * p) = o;
        int tile = node >> 4, lr = node & 15, ck = p >> 2, q = p & 3;
        *(uint4*)(XHp + (((size_t)tile * 4 + ck) * 64 + q * 16 + lr) * 8) = o;
    } else {
        int i = (b - CSR_BLOCKS - CONCAT_BLOCKS) * 256 + threadIdx.x;
        if (i < 20 * 8 * 64 * 8) {
            int j = i & 7, lane = (i >> 3) & 63, nt = (i >> 9) & 7, ks = i >> 12;
            int k = ks * 32 + (lane >> 4) * 8 + j;
            int nn = nt * 16 + (lane & 15);
            Wzrf[i] = f2bfu(zr_val(Wz, Wr, k, nn));
        } else if (i < 20 * 8 * 64 * 8 + 20 * 4 * 64 * 8) {
            int i2 = i - 20 * 8 * 64 * 8;
            int j = i2 & 7, lane = (i2 >> 3) & 63, nt = (i2 >> 9) & 3, ks = i2 >> 11;
            int k = ks * 32 + (lane >> 4) * 8 + j;
            int nn = nt * 16 + (lane & 15);
            Whf[i2] = f2bfu(h_val(Wh, k, nn));
        }
    }
}

// ---------------- prop1 kernels ----------------
// P1 row-major [n][256] + fragment-packed P1p; Q1 row-major [n][128] + Q1p.

__global__ void prop1_128(const unsigned short* __restrict__ S,
                          const int* __restrict__ rowptr, const int* __restrict__ src,
                          const float2* __restrict__ w,
                          unsigned short* __restrict__ P1, unsigned short* __restrict__ P1p,
                          int n) {
    int tid = blockIdx.x * blockDim.x + threadIdx.x;
    int lane = tid & 63;
    int node = ((tid >> 6) << 1) + (lane >> 5);
    int p = lane & 31;
    if (node >= n) return;
    int beg = rowptr[node], end = rowptr[node + 1];
    float ao0 = 0.f, ao1 = 0.f, ao2 = 0.f, ao3 = 0.f;
    float ai0 = 0.f, ai1 = 0.f, ai2 = 0.f, ai3 = 0.f;
    int j = beg;
#define P1STEP(s_, w_) {                                                     \
        uint2 u = *(const uint2*)(S + (size_t)(s_) * 128 + 4 * p);           \
        float c0 = bflo(u.x), c1 = bfhi(u.x), c2 = bflo(u.y), c3 = bfhi(u.y);\
        ao0 = fmaf(w_.x, c0, ao0); ao1 = fmaf(w_.x, c1, ao1);                \
        ao2 = fmaf(w_.x, c2, ao2); ao3 = fmaf(w_.x, c3, ao3);                \
        ai0 = fmaf(w_.y, c0, ai0); ai1 = fmaf(w_.y, c1, ai1);                \
        ai2 = fmaf(w_.y, c2, ai2); ai3 = fmaf(w_.y, c3, ai3); }
    for (; j + 8 <= end; j += 8) {
        int s0 = src[j], s1 = src[j + 1], s2 = src[j + 2], s3 = src[j + 3];
        int s4 = src[j + 4], s5 = src[j + 5], s6 = src[j + 6], s7 = src[j + 7];
        float2 w0 = w[j], w1 = w[j + 1], w2 = w[j + 2], w3 = w[j + 3];
        float2 w4 = w[j + 4], w5 = w[j + 5], w6 = w[j + 6], w7 = w[j + 7];
        P1STEP(s0, w0); P1STEP(s1, w1); P1STEP(s2, w2); P1STEP(s3, w3);
        P1STEP(s4, w4); P1STEP(s5, w5); P1STEP(s6, w6); P1STEP(s7, w7);
    }
    for (; j + 4 <= end; j += 4) {
        int s0 = src[j], s1 = src[j + 1], s2 = src[j + 2], s3 = src[j + 3];
        float2 w0 = w[j], w1 = w[j + 1], w2 = w[j + 2], w3 = w[j + 3];
        P1STEP(s0, w0); P1STEP(s1, w1); P1STEP(s2, w2); P1STEP(s3, w3);
    }
    for (; j < end; ++j) {
        int s = src[j]; float2 wv = w[j];
        P1STEP(s, wv);
    }
#undef P1STEP
    uint4 o;
    o.x = packbf(ao0, ao1); o.y = packbf(ai0, ai1);
    o.z = packbf(ao2, ao3); o.w = packbf(ai2, ai3);
    *(uint4*)(P1 + (size_t)node * 256 + 8 * p) = o;
    int tile = node >> 4, lr = node & 15, ck = p >> 2, q = p & 3;
    *(uint4*)(P1p + (((size_t)tile * 8 + ck) * 64 + q * 16 + lr) * 8) = o;
}

__global__ void prop1_64(const unsigned short* __restrict__ HR,
                         const int* __restrict__ rowptr, const int* __restrict__ src,
                         const float2* __restrict__ w,
                         unsigned short* __restrict__ Q1, unsigned short* __restrict__ Q1p,
                         int n) {
    int tid = blockIdx.x * blockDim.x + threadIdx.x;
    int lane = tid & 63;
    int node = ((tid >> 6) << 2) + (lane >> 4);
    int p = lane & 15;
    if (node >= n) return;
    int beg = rowptr[node], end = rowptr[node + 1];
    float ao0 = 0.f, ao1 = 0.f, ao2 = 0.f, ao3 = 0.f;
    float ai0 = 0.f, ai1 = 0.f, ai2 = 0.f, ai3 = 0.f;
    int j = beg;
#define Q1STEP(s_, w_) {                                                     \
        uint2 u = *(const uint2*)(HR + (size_t)(s_) * 64 + 4 * p);           \
        float c0 = bflo(u.x), c1 = bfhi(u.x), c2 = bflo(u.y), c3 = bfhi(u.y);\
        ao0 = fmaf(w_.x, c0, ao0); ao1 = fmaf(w_.x, c1, ao1);                \
        ao2 = fmaf(w_.x, c2, ao2); ao3 = fmaf(w_.x, c3, ao3);                \
        ai0 = fmaf(w_.y, c0, ai0); ai1 = fmaf(w_.y, c1, ai1);                \
        ai2 = fmaf(w_.y, c2, ai2); ai3 = fmaf(w_.y, c3, ai3); }
    for (; j + 8 <= end; j += 8) {
        int s0 = src[j], s1 = src[j + 1], s2 = src[j + 2], s3 = src[j + 3];
        int s4 = src[j + 4], s5 = src[j + 5], s6 = src[j + 6], s7 = src[j + 7];
        float2 w0 = w[j], w1 = w[j + 1], w2 = w[j + 2], w3 = w[j + 3];
        float2 w4 = w[j + 4], w5 = w[j + 5], w6 = w[j + 6], w7 = w[j + 7];
        Q1STEP(s0, w0); Q1STEP(s1, w1); Q1STEP(s2, w2); Q1STEP(s3, w3);
        Q1STEP(s4, w4); Q1STEP(s5, w5); Q1STEP(s6, w6); Q1STEP(s7, w7);
    }
    for (; j + 4 <= end; j += 4) {
        int s0 = src[j], s1 = src[j + 1], s2 = src[j + 2], s3 = src[j + 3];
        float2 w0 = w[j], w1 = w[j + 1], w2 = w[j + 2], w3 = w[j + 3];
        Q1STEP(s0, w0); Q1STEP(s1, w1); Q1STEP(s2, w2); Q1STEP(s3, w3);
    }
    for (; j < end; ++j) {
        int s = src[j]; float2 wv = w[j];
        Q1STEP(s, wv);
    }
#undef Q1STEP
    uint4 o;
    o.x = packbf(ao0, ao1); o.y = packbf(ai0, ai1);
    o.z = packbf(ao2, ao3); o.w = packbf(ai2, ai3);
    *(uint4*)(Q1 + (size_t)node * 128 + 8 * p) = o;
    int tile = node >> 4, lr = node & 15, ck = p >> 2, q = p & 3;
    *(uint4*)(Q1p + (((size_t)tile * 4 + ck) * 64 + q * 16 + lr) * 8) = o;
}

// ---------------- fused prop2 + GEMM kernels ----------------
// mfma_f32_16x16x32_bf16: A[m=lane&15][k=quad*8+j]; B same-k at n=lane&15;
// C/D: col=lane&15, row=(lane>>4)*4+reg.
// LDS frag rows padded to 65 uint4 (write conflicts 32-way -> 4-way; reads contiguous).

// F3: prop2 on P1 (full 256 cols) -> LDS P2, then ZR GEMM. Block = 64 nodes.
__global__ __launch_bounds__(256) void prop2_gemm_zr(
    const unsigned short* __restrict__ P1, const unsigned short* __restrict__ Xc,
    const int* __restrict__ rowptr, const int* __restrict__ src,
    const float2* __restrict__ w,
    const unsigned short* __restrict__ XHp, const unsigned short* __restrict__ P1p,
    unsigned short* __restrict__ P2xp,
    const unsigned short* __restrict__ Wf, const float* __restrict__ bz,
    const float* __restrict__ br, const float* __restrict__ H,
    float* __restrict__ Zf, unsigned short* __restrict__ HR, int n) {
    __shared__ unsigned short P2l[32 * 65 * 8];   // 33280 B
    int tid = threadIdx.x;
    int lane = tid & 63;
    int wid = tid >> 6;
    int rowbase = blockIdx.x * 64;
    int half = lane >> 5, p = lane & 31;

    // ---- prop2 phase: 16 nodes per wave ----
    for (int iter = 0; iter < 8; ++iter) {
        int nl = wid * 16 + iter * 2 + half;
        int node = rowbase + nl;
        uint4 o = make_uint4(0u, 0u, 0u, 0u);
        if (node < n) {
            int beg = rowptr[node], end = rowptr[node + 1];
            float oa = 0.f, ob = 0.f, oc = 0.f, od = 0.f;
            float ia = 0.f, ib = 0.f, ic = 0.f, id = 0.f;
            int j = beg;
#define P2STEP(s_, w_) {                                                     \
        uint4 v = *(const uint4*)(P1 + (size_t)(s_) * 256 + 8 * p);          \
        oa = fmaf(w_.x, bflo(v.x), oa); ob = fmaf(w_.x, bfhi(v.x), ob);      \
        ia = fmaf(w_.y, bflo(v.y), ia); ib = fmaf(w_.y, bfhi(v.y), ib);      \
        oc = fmaf(w_.x, bflo(v.z), oc); od = fmaf(w_.x, bfhi(v.z), od);      \
        ic = fmaf(w_.y, bflo(v.w), ic); id = fmaf(w_.y, bfhi(v.w), id); }
            for (; j + 4 <= end; j += 4) {
                int s0 = src[j], s1 = src[j + 1], s2 = src[j + 2], s3 = src[j + 3];
                float2 w0 = w[j], w1 = w[j + 1], w2 = w[j + 2], w3 = w[j + 3];
                P2STEP(s0, w0); P2STEP(s1, w1); P2STEP(s2, w2); P2STEP(s3, w3);
            }
            for (; j < end; ++j) {
                int s = src[j]; float2 wv = w[j];
                P2STEP(s, wv);
            }
#undef P2STEP
            uint2 ux = *(const uint2*)(Xc + (size_t)node * 128 + 4 * p);
            float xa = bflo(ux.x), xb = bfhi(ux.x), xc2 = bflo(ux.y), xd = bfhi(ux.y);
            o.x = packbf(2.f * oa - xa, 2.f * ob - xb);
            o.y = packbf(2.f * ia - xa, 2.f * ib - xb);
            o.z = packbf(2.f * oc - xc2, 2.f * od - xd);
            o.w = packbf(2.f * ic - xc2, 2.f * id - xd);
        }
        int mtile = nl >> 4, lr = nl & 15, ck = p >> 2, q = p & 3;
        *(uint4*)&P2l[((mtile * 8 + ck) * 65 + q * 16 + lr) * 8] = o;
        if (ck < 4 && node < n) {   // export X-half for the H GEMM
            int gtile = node >> 4;
            *(uint4*)(P2xp + (((size_t)gtile * 4 + ck) * 64 + q * 16 + lr) * 8) = o;
        }
    }
    __syncthreads();

    // ---- GEMM phase: 4 waves, each 64 rows x 32 cols ----
    int ngrp = wid;
    int lr = lane & 15, quad = lane >> 4;
    int tiles[4];
#pragma unroll
    for (int mt = 0; mt < 4; ++mt) {
        int t = (rowbase >> 4) + mt;
        tiles[mt] = (t > N_TILES - 1) ? N_TILES - 1 : t;
    }

    f32x4 zero = {0.f, 0.f, 0.f, 0.f};
    f32x4 acc[4][2];
#pragma unroll
    for (int a = 0; a < 4; ++a)
#pragma unroll
        for (int b = 0; b < 2; ++b) acc[a][b] = zero;

#pragma unroll
    for (int ks = 0; ks < 20; ++ks) {
        bf8 b0 = *(const bf8*)(Wf + (((size_t)ks * 8 + ngrp * 2 + 0) * 64 + lane) * 8);
        bf8 b1 = *(const bf8*)(Wf + (((size_t)ks * 8 + ngrp * 2 + 1) * 64 + lane) * 8);
#pragma unroll
        for (int mt = 0; mt < 4; ++mt) {
            bf8 a;
            if (ks < 4) {
                a = *(const bf8*)(XHp + (((size_t)tiles[mt] * 4 + ks) * 64 + lane) * 8);
            } else if (ks < 12) {
                a = *(const bf8*)(P1p + (((size_t)tiles[mt] * 8 + (ks - 4)) * 64 + lane) * 8);
            } else {
                a = *(const bf8*)&P2l[((mt * 8 + (ks - 12)) * 65 + lane) * 8];
            }
            acc[mt][0] = __builtin_amdgcn_mfma_f32_16x16x32_bf16(a, b0, acc[mt][0], 0, 0, 0);
            acc[mt][1] = __builtin_amdgcn_mfma_f32_16x16x32_bf16(a, b1, acc[mt][1], 0, 0, 0);
        }
    }
#pragma unroll
    for (int mt = 0; mt < 4; ++mt)
#pragma unroll
        for (int reg = 0; reg < 4; ++reg) {
            int r = rowbase + mt * 16 + quad * 4 + reg;
            if (r >= n) continue;
#pragma unroll
            for (int nt = 0; nt < 2; ++nt) {
                int cidx = ngrp * 32 + nt * 16 + lr;
                float bias = (cidx < 64) ? bz[cidx] : br[cidx - 64];
                float v = acc[mt][nt][reg] + bias;
                float s = 1.f / (1.f + expf(-v));
                if (cidx < 64) {
                    Zf[(size_t)r * 64 + cidx] = s;
                } else {
                    int c2 = cidx - 64;
                    HR[(size_t)r * 64 + c2] = f2bfu(H[(size_t)r * 64 + c2] * s);
                }
            }
        }
}

// F5: prop2 on Q1 (128 cols) -> LDS Q2, then H GEMM + GRU. Block = 128 nodes.
__global__ __launch_bounds__(256) void prop2_gemm_h(
    const unsigned short* __restrict__ Q1, const unsigned short* __restrict__ HR,
    const int* __restrict__ rowptr, const int* __restrict__ src,
    const float2* __restrict__ w,
    const unsigned short* __restrict__ XHp, const unsigned short* __restrict__ P1p,
    const unsigned short* __restrict__ P2xp, const unsigned short* __restrict__ Q1p,
    const unsigned short* __restrict__ Wf, const float* __restrict__ bh,
    const float* __restrict__ Zf, const float* __restrict__ H,
    float* __restrict__ out, int n) {
    __shared__ unsigned short Q2l[32 * 65 * 8];   // 33280 B
    int tid = threadIdx.x;
    int lane = tid & 63;
    int wid = tid >> 6;
    int rowbase = blockIdx.x * 128;
    int quarter = lane >> 4, p = lane & 15;

    // ---- prop2 phase: 32 nodes per wave ----
    for (int iter = 0; iter < 8; ++iter) {
        int nl = wid * 32 + iter * 4 + quarter;
        int node = rowbase + nl;
        uint4 o = make_uint4(0u, 0u, 0u, 0u);
        if (node < n) {
            int beg = rowptr[node], end = rowptr[node + 1];
            float oa = 0.f, ob = 0.f, oc = 0.f, od = 0.f;
            float ia = 0.f, ib = 0.f, ic = 0.f, id = 0.f;
            int j = beg;
#define Q2STEP(s_, w_) {                                                     \
        uint4 v = *(const uint4*)(Q1 + (size_t)(s_) * 128 + 8 * p);          \
        oa = fmaf(w_.x, bflo(v.x), oa); ob = fmaf(w_.x, bfhi(v.x), ob);      \
        ia = fmaf(w_.y, bflo(v.y), ia); ib = fmaf(w_.y, bfhi(v.y), ib);      \
        oc = fmaf(w_.x, bflo(v.z), oc); od = fmaf(w_.x, bfhi(v.z), od);      \
        ic = fmaf(w_.y, bflo(v.w), ic); id = fmaf(w_.y, bfhi(v.w), id); }
            for (; j + 4 <= end; j += 4) {
                int s0 = src[j], s1 = src[j + 1], s2 = src[j + 2], s3 = src[j + 3];
                float2 w0 = w[j], w1 = w[j + 1], w2 = w[j + 2], w3 = w[j + 3];
                Q2STEP(s0, w0); Q2STEP(s1, w1); Q2STEP(s2, w2); Q2STEP(s3, w3);
            }
            for (; j < end; ++j) {
                int s = src[j]; float2 wv = w[j];
                Q2STEP(s, wv);
            }
#undef Q2STEP
            uint2 ux = *(const uint2*)(HR + (size_t)node * 64 + 4 * p);
            float xa = bflo(ux.x), xb = bfhi(ux.x), xc2 = bflo(ux.y), xd = bfhi(ux.y);
            o.x = packbf(2.f * oa - xa, 2.f * ob - xb);
            o.y = packbf(2.f * ia - xa, 2.f * ib - xb);
            o.z = packbf(2.f * oc - xc2, 2.f * od - xd);
            o.w = packbf(2.f * ic - xc2, 2.f * id - xd);
        }
        int mtile = nl >> 4, lr = nl & 15, ck = p >> 2, q = p & 3;
        *(uint4*)&Q2l[((mtile * 4 + ck) * 65 + q * 16 + lr) * 8] = o;
    }
    __syncthreads();

    // ---- GEMM phase: (mh = wid&1 row-half, ngrp = wid>>1), 64 rows x 32 cols ----
    int mh = wid & 1, ngrp = wid >> 1;
    int rb = rowbase + mh * 64;
    int lr = lane & 15, quad = lane >> 4;
    int tiles[4];
    const unsigned short* hrp[4];
#pragma unroll
    for (int mt = 0; mt < 4; ++mt) {
        int t = (rb >> 4) + mt;
        tiles[mt] = (t > N_TILES - 1) ? N_TILES - 1 : t;
        int r = rb + mt * 16 + lr;
        if (r >= n) r = n - 1;
        hrp[mt] = HR + (size_t)r * 64 + quad * 8;
    }

    f32x4 zero = {0.f, 0.f, 0.f, 0.f};
    f32x4 acc[4][2];
#pragma unroll
    for (int a = 0; a < 4; ++a)
#pragma unroll
        for (int b = 0; b < 2; ++b) acc[a][b] = zero;

#pragma unroll
    for (int ks = 0; ks < 20; ++ks) {
        bf8 b0 = *(const bf8*)(Wf + (((size_t)ks * 4 + ngrp * 2 + 0) * 64 + lane) * 8);
        bf8 b1 = *(const bf8*)(Wf + (((size_t)ks * 4 + ngrp * 2 + 1) * 64 + lane) * 8);
#pragma unroll
        for (int mt = 0; mt < 4; ++mt) {
            bf8 a;
            if (ks < 2) {
                a = *(const bf8*)(XHp + (((size_t)tiles[mt] * 4 + ks) * 64 + lane) * 8);
            } else if (ks < 6) {
                a = *(const bf8*)(P1p + (((size_t)tiles[mt] * 8 + (ks - 2)) * 64 + lane) * 8);
            } else if (ks < 10) {
                a = *(const bf8*)(P2xp + (((size_t)tiles[mt] * 4 + (ks - 6)) * 64 + lane) * 8);
            } else if (ks < 12) {
                a = *(const bf8*)(hrp[mt] + (ks - 10) * 32);
            } else if (ks < 16) {
                a = *(const bf8*)(Q1p + (((size_t)tiles[mt] * 4 + (ks - 12)) * 64 + lane) * 8);
            } else {
                a = *(const bf8*)&Q2l[(((mh * 4 + mt) * 4 + (ks - 16)) * 65 + lane) * 8];
            }
            acc[mt][0] = __builtin_amdgcn_mfma_f32_16x16x32_bf16(a, b0, acc[mt][0], 0, 0, 0);
            acc[mt][1] = __builtin_amdgcn_mfma_f32_16x16x32_bf16(a, b1, acc[mt][1], 0, 0, 0);
        }
    }
#pragma unroll
    for (int mt = 0; mt < 4; ++mt)
#pragma unroll
        for (int reg = 0; reg < 4; ++reg) {
            int r = rb + mt * 16 + quad * 4 + reg;
            if (r >= n) continue;
#pragma unroll
            for (int nt = 0; nt < 2; ++nt) {
                int cidx = ngrp * 32 + nt * 16 + lr;
                float ht = tanhf(acc[mt][nt][reg] + bh[cidx]);
                float z = Zf[(size_t)r * 64 + cidx];
                float h_old = H[(size_t)r * 64 + cidx];
                out[(size_t)r * 64 + cidx] = z * h_old + (1.f - z) * ht;
            }
        }
}

// ---------------- launch ----------------

static inline size_t rup(size_t x) { return (x + 63) & ~(size_t)63; }

extern "C" void kernel_launch(void* const* d_in, const int* in_sizes, int n_in,
                              void* d_out, int out_size, void* d_ws, size_t ws_size,
                              hipStream_t stream) {
    const float* X  = (const float*)d_in[0];
    const int*   EI = (const int*)d_in[1];
    const float* H  = (const float*)d_in[2];
    const float* Wz = (const float*)d_in[3];
    const float* bz = (const float*)d_in[4];
    const float* Wr = (const float*)d_in[5];
    const float* br = (const float*)d_in[6];
    const float* Wh = (const float*)d_in[7];
    const float* bh = (const float*)d_in[8];
    float* out = (float*)d_out;

    const int* row = EI;
    const int* col = EI + N_EDGES;

    char* ws = (char*)d_ws;
    size_t off = 0;
    auto carve = [&](size_t bytes) { void* p = ws + off; off += rup(bytes); return p; };

    int*   deg_out   = (int*)carve(N_NODES * 4);
    int*   deg_in    = (int*)carve(N_NODES * 4);
    int*   rowptr    = (int*)carve((N_NODES + 1) * 4);
    int*   cursor    = (int*)carve(N_NODES * 4);
    int*   blocksums = (int*)carve(64 * 4);
    float2* winv     = (float2*)carve(N_NODES * 8);
    int*   csr_src   = (int*)carve(N_EDGES * 4);
    float2* csr_w    = (float2*)carve(N_EDGES * 8);
    unsigned short* XH  = (unsigned short*)carve((size_t)N_NODES * 128 * 2);  // dead after prop2_gemm_zr
    unsigned short* P1  = (unsigned short*)carve((size_t)N_NODES * 256 * 2);  // dead after prop2_gemm_zr
    unsigned short* XHp = (unsigned short*)carve((size_t)N_TILES * 4 * 512 * 2);
    unsigned short* P1p = (unsigned short*)carve((size_t)N_TILES * 8 * 512 * 2);
    unsigned short* P2xp = (unsigned short*)carve((size_t)N_TILES * 4 * 512 * 2);
    unsigned short* HR  = (unsigned short*)carve((size_t)N_NODES * 64 * 2);
    float* Zf           = (float*)carve((size_t)N_NODES * 64 * 4);
    unsigned short* Wzrf = (unsigned short*)carve(20 * 8 * 64 * 8 * 2);
    unsigned short* Whf  = (unsigned short*)carve(20 * 4 * 64 * 8 * 2);

    // Aliases (dead regions reused after prop2_gemm_zr):
    unsigned short* Q1  = XH;                                  // [n][128] row-major
    unsigned short* Q1p = P1;                                  // fragment-packed, 12.8 MB

    hipMemsetAsync(deg_out, 0, rup(N_NODES * 4) + rup(N_NODES * 4), stream);
    count_deg<<<(N_EDGES + 255) / 256, 256, 0, stream>>>(row, col, deg_out, deg_in, N_EDGES);

    int nblk = (N_NODES + 1023) / 1024;
    scan_block<<<nblk, 1024, 0, stream>>>(deg_in, rowptr, blocksums, N_NODES);
    scan_sums<<<1, 64, 0, stream>>>(blocksums, nblk);
    scan_add<<<(N_NODES + 1 + 255) / 256, 256, 0, stream>>>(rowptr, blocksums, cursor,
                                                            deg_out, deg_in, winv, N_NODES, N_EDGES);

    // fused: build_csr + concat_xh + pack_weights
    fused_prep<<<CSR_BLOCKS + CONCAT_BLOCKS + PACK_BLOCKS, 256, 0, stream>>>(
        row, col, winv, cursor, csr_src, csr_w,
        X, H, XH, XHp, Wz, Wr, Wh, Wzrf, Whf, N_NODES, N_EDGES);

    // prop1 on XH: 2 nodes/wave
    int blocks_p128 = (((N_NODES + 1) / 2) * 64 + 255) / 256;
    prop1_128<<<blocks_p128, 256, 0, stream>>>(XH, rowptr, csr_src, csr_w, P1, P1p, N_NODES);

    // fused prop2 + ZR GEMM -> Zf, HR, P2xp
    int zr_blocks = (N_NODES + 63) / 64;
    prop2_gemm_zr<<<zr_blocks, 256, 0, stream>>>(P1, XH, rowptr, csr_src, csr_w,
                                                 XHp, P1p, P2xp, Wzrf, bz, br, H,
                                                 Zf, HR, N_NODES);

    // prop1 on HR: 4 nodes/wave  (XH, P1 row-major now dead -> Q1, Q1p aliases)
    int blocks_p64 = (((N_NODES + 3) / 4) * 64 + 255) / 256;
    prop1_64<<<blocks_p64, 256, 0, stream>>>(HR, rowptr, csr_src, csr_w, Q1, Q1p, N_NODES);

    // fused prop2 + H GEMM + GRU mix -> out
    int h_blocks = (N_NODES + 127) / 128;
    prop2_gemm_h<<<h_blocks, 256, 0, stream>>>(Q1, HR, rowptr, csr_src, csr_w,
                                               XHp, P1p, P2xp, Q1p, Whf, bh,
                                               Zf, H, out, N_NODES);
}

// Round 9
// 362.568 us; speedup vs baseline: 1.0406x; 1.0406x over previous
//
#include <hip/hip_runtime.h>
#include <hip/hip_bf16.h>
#include <math.h>

#define N_NODES 50000
#define N_EDGES 500000
#define C_DIM 128
#define N_TILES 3125   // 50000/16 exact

#define CSR_BLOCKS 1954      // ceil(500000/256)
#define CONCAT_BLOCKS 3125   // 50000*16/256
#define PACK_BLOCKS 480      // (20*8*512 + 20*4*512)/256

typedef __attribute__((ext_vector_type(8))) short bf8;
typedef __attribute__((ext_vector_type(4))) float f32x4;

__device__ __forceinline__ float bflo(unsigned u) { return __uint_as_float(u << 16); }
__device__ __forceinline__ float bfhi(unsigned u) { return __uint_as_float(u & 0xffff0000u); }
__device__ __forceinline__ unsigned short f2bfu(float f) {
    __hip_bfloat16 h = __float2bfloat16(f);
    unsigned short u;
    __builtin_memcpy(&u, &h, 2);
    return u;
}
__device__ __forceinline__ unsigned packbf(float a, float b) {
    return ((unsigned)f2bfu(b) << 16) | f2bfu(a);
}

// ---------------- graph preprocessing ----------------

__global__ void count_deg(const int* __restrict__ row, const int* __restrict__ col,
                          int* __restrict__ dout, int* __restrict__ din, int e) {
    int i = blockIdx.x * blockDim.x + threadIdx.x;
    if (i >= e) return;
    atomicAdd(&dout[row[i]], 1);
    atomicAdd(&din[col[i]], 1);
}

__global__ void scan_block(const int* __restrict__ counts, int* __restrict__ excl,
                           int* __restrict__ blocksums, int n) {
    __shared__ int tmp[1024];
    int tid = threadIdx.x;
    int gid = blockIdx.x * 1024 + tid;
    int v = (gid < n) ? counts[gid] : 0;
    tmp[tid] = v;
    __syncthreads();
    for (int off = 1; off < 1024; off <<= 1) {
        int t = (tid >= off) ? tmp[tid - off] : 0;
        __syncthreads();
        tmp[tid] += t;
        __syncthreads();
    }
    int incl = tmp[tid];
    if (gid < n) excl[gid] = incl - v;
    if (tid == 1023) blocksums[blockIdx.x] = incl;
}

__global__ void scan_sums(int* __restrict__ blocksums, int nb) {
    __shared__ int tmp[64];
    int tid = threadIdx.x;
    int v = (tid < nb) ? blocksums[tid] : 0;
    tmp[tid] = v;
    __syncthreads();
    for (int off = 1; off < 64; off <<= 1) {
        int t = (tid >= off) ? tmp[tid - off] : 0;
        __syncthreads();
        tmp[tid] += t;
        __syncthreads();
    }
    if (tid < nb) blocksums[tid] = tmp[tid] - v;
}

__global__ void scan_add(int* __restrict__ rowptr, const int* __restrict__ blocksums,
                         int* __restrict__ cursor, const int* __restrict__ dout,
                         const int* __restrict__ din, float2* __restrict__ winv,
                         int n, int e_total) {
    int gid = blockIdx.x * blockDim.x + threadIdx.x;
    if (gid < n) {
        int v = rowptr[gid] + blocksums[gid >> 10];
        rowptr[gid] = v;
        cursor[gid] = v;
        winv[gid] = make_float2(1.0f / (float)dout[gid], 1.0f / (float)din[gid]);
    }
    if (gid == n) rowptr[n] = e_total;
}

// ---------------- weight helpers ----------------
__device__ __forceinline__ float wraw(const float* W, int d, int kk, int k, int j) {
    return W[((d * 3 + kk) * 128 + k) * 64 + j];
}

__device__ __forceinline__ float zr_val(const float* Wz, const float* Wr, int k, int nn) {
    const float* W = (nn < 64) ? Wz : Wr;
    int j = nn & 63;
    if (k < 128) return wraw(W, 0, 0, k, j) + wraw(W, 1, 0, k, j);
    int k2 = k - 128;
    int kk = (k2 >= 256) ? 2 : 1;
    int k3 = k2 & 255;
    int p = k3 >> 2, sub = k3 & 3;
    return wraw(W, sub >> 1, kk, 2 * p + (sub & 1), j);
}

__device__ __forceinline__ float h_val(const float* Wh, int k, int j) {
    if (k < 64) return wraw(Wh, 0, 0, k, j) + wraw(Wh, 1, 0, k, j);
    if (k < 320) {
        int k2 = k - 64;
        int kk = (k2 >= 128) ? 2 : 1;
        int k3 = k2 & 127;
        int p = k3 >> 2, sub = k3 & 3;
        return wraw(Wh, sub >> 1, kk, 2 * p + (sub & 1), j);
    }
    if (k < 384) return wraw(Wh, 0, 0, 64 + (k - 320), j) + wraw(Wh, 1, 0, 64 + (k - 320), j);
    int k2 = k - 384;
    int kk = (k2 >= 128) ? 2 : 1;
    int k3 = k2 & 127;
    int p = k3 >> 2, sub = k3 & 3;
    return wraw(Wh, sub >> 1, kk, 64 + 2 * p + (sub & 1), j);
}

// ---------------- fused prep: build_csr + concat_xh + pack_weights ----------
__global__ void fused_prep(const int* __restrict__ row, const int* __restrict__ col,
                           const float2* __restrict__ winv, int* __restrict__ cursor,
                           int* __restrict__ csr_src, float2* __restrict__ csr_w,
                           const float* __restrict__ X, const float* __restrict__ Hm,
                           unsigned short* __restrict__ XH, unsigned short* __restrict__ XHp,
                           const float* __restrict__ Wz, const float* __restrict__ Wr,
                           const float* __restrict__ Wh,
                           unsigned short* __restrict__ Wzrf, unsigned short* __restrict__ Whf,
                           int n, int e) {
    int b = blockIdx.x;
    if (b < CSR_BLOCKS) {
        int i = b * 256 + threadIdx.x;
        if (i >= e) return;
        int r = row[i], c = col[i];
        int pos = atomicAdd(&cursor[c], 1);
        csr_src[pos] = r;
        csr_w[pos] = winv[r];
    } else if (b < CSR_BLOCKS + CONCAT_BLOCKS) {
        int t = (b - CSR_BLOCKS) * 256 + threadIdx.x;   // < n*16 exactly
        int node = t >> 4, p = t & 15;
        const float* src = (p < 8) ? (X + (size_t)node * 64 + 8 * p)
                                   : (Hm + (size_t)node * 64 + 8 * (p - 8));
        float4 v0 = *(const float4*)src;
        float4 v1 = *(const float4*)(src + 4);
        uint4 o;
        o.x = packbf(v0.x, v0.y); o.y = packbf(v0.z, v0.w);
        o.z = packbf(v1.x, v1.y); o.w = packbf(v1.z, v1.w);
        *(uint4*)(XH + (size_t)node * 128 + 8 * p) = o;
        int tile = node >> 4, lr = node & 15, ck = p >> 2, q = p & 3;
        *(uint4*)(XHp + (((size_t)tile * 4 + ck) * 64 + q * 16 + lr) * 8) = o;
    } else {
        int i = (b - CSR_BLOCKS - CONCAT_BLOCKS) * 256 + threadIdx.x;
        if (i < 20 * 8 * 64 * 8) {
            int j = i & 7, lane = (i >> 3) & 63, nt = (i >> 9) & 7, ks = i >> 12;
            int k = ks * 32 + (lane >> 4) * 8 + j;
            int nn = nt * 16 + (lane & 15);
            Wzrf[i] = f2bfu(zr_val(Wz, Wr, k, nn));
        } else if (i < 20 * 8 * 64 * 8 + 20 * 4 * 64 * 8) {
            int i2 = i - 20 * 8 * 64 * 8;
            int j = i2 & 7, lane = (i2 >> 3) & 63, nt = (i2 >> 9) & 3, ks = i2 >> 11;
            int k = ks * 32 + (lane >> 4) * 8 + j;
            int nn = nt * 16 + (lane & 15);
            Whf[i2] = f2bfu(h_val(Wh, k, nn));
        }
    }
}

// ---------------- diffusion props ----------------
// P1 row-major [n][256] + packed P1p; P2 packed-only. Q1 row-major [n][128] +
// packed Q1p; Q2 packed-only. Packed: T[tile][ck][lane][8].

__global__ void prop1_128(const unsigned short* __restrict__ S,
                          const int* __restrict__ rowptr, const int* __restrict__ src,
                          const float2* __restrict__ w,
                          unsigned short* __restrict__ P1, unsigned short* __restrict__ P1p,
                          int n) {
    int tid = blockIdx.x * blockDim.x + threadIdx.x;
    int lane = tid & 63;
    int node = ((tid >> 6) << 1) + (lane >> 5);
    int p = lane & 31;
    if (node >= n) return;
    int beg = rowptr[node], end = rowptr[node + 1];
    float ao0 = 0.f, ao1 = 0.f, ao2 = 0.f, ao3 = 0.f;
    float ai0 = 0.f, ai1 = 0.f, ai2 = 0.f, ai3 = 0.f;
    int j = beg;
#define P1STEP(s_, w_) {                                                     \
        uint2 u = *(const uint2*)(S + (size_t)(s_) * 128 + 4 * p);           \
        float c0 = bflo(u.x), c1 = bfhi(u.x), c2 = bflo(u.y), c3 = bfhi(u.y);\
        ao0 = fmaf(w_.x, c0, ao0); ao1 = fmaf(w_.x, c1, ao1);                \
        ao2 = fmaf(w_.x, c2, ao2); ao3 = fmaf(w_.x, c3, ao3);                \
        ai0 = fmaf(w_.y, c0, ai0); ai1 = fmaf(w_.y, c1, ai1);                \
        ai2 = fmaf(w_.y, c2, ai2); ai3 = fmaf(w_.y, c3, ai3); }
    for (; j + 8 <= end; j += 8) {
        int s0 = src[j], s1 = src[j + 1], s2 = src[j + 2], s3 = src[j + 3];
        int s4 = src[j + 4], s5 = src[j + 5], s6 = src[j + 6], s7 = src[j + 7];
        float2 w0 = w[j], w1 = w[j + 1], w2 = w[j + 2], w3 = w[j + 3];
        float2 w4 = w[j + 4], w5 = w[j + 5], w6 = w[j + 6], w7 = w[j + 7];
        P1STEP(s0, w0); P1STEP(s1, w1); P1STEP(s2, w2); P1STEP(s3, w3);
        P1STEP(s4, w4); P1STEP(s5, w5); P1STEP(s6, w6); P1STEP(s7, w7);
    }
    for (; j + 4 <= end; j += 4) {
        int s0 = src[j], s1 = src[j + 1], s2 = src[j + 2], s3 = src[j + 3];
        float2 w0 = w[j], w1 = w[j + 1], w2 = w[j + 2], w3 = w[j + 3];
        P1STEP(s0, w0); P1STEP(s1, w1); P1STEP(s2, w2); P1STEP(s3, w3);
    }
    for (; j < end; ++j) {
        int s = src[j]; float2 wv = w[j];
        P1STEP(s, wv);
    }
#undef P1STEP
    uint4 o;
    o.x = packbf(ao0, ao1); o.y = packbf(ai0, ai1);
    o.z = packbf(ao2, ao3); o.w = packbf(ai2, ai3);
    *(uint4*)(P1 + (size_t)node * 256 + 8 * p) = o;
    int tile = node >> 4, lr = node & 15, ck = p >> 2, q = p & 3;
    *(uint4*)(P1p + (((size_t)tile * 8 + ck) * 64 + q * 16 + lr) * 8) = o;
}

__global__ void prop2_128(const unsigned short* __restrict__ P1,
                          const unsigned short* __restrict__ Xc,
                          const int* __restrict__ rowptr, const int* __restrict__ src,
                          const float2* __restrict__ w,
                          unsigned short* __restrict__ P2p, int n) {
    int tid = blockIdx.x * blockDim.x + threadIdx.x;
    int lane = tid & 63;
    int node = ((tid >> 6) << 1) + (lane >> 5);
    int p = lane & 31;
    if (node >= n) return;
    int beg = rowptr[node], end = rowptr[node + 1];
    float oa = 0.f, ob = 0.f, oc = 0.f, od = 0.f;
    float ia = 0.f, ib = 0.f, ic = 0.f, id = 0.f;
    int j = beg;
#define P2STEP(s_, w_) {                                                     \
        uint4 v = *(const uint4*)(P1 + (size_t)(s_) * 256 + 8 * p);          \
        oa = fmaf(w_.x, bflo(v.x), oa); ob = fmaf(w_.x, bfhi(v.x), ob);      \
        ia = fmaf(w_.y, bflo(v.y), ia); ib = fmaf(w_.y, bfhi(v.y), ib);      \
        oc = fmaf(w_.x, bflo(v.z), oc); od = fmaf(w_.x, bfhi(v.z), od);      \
        ic = fmaf(w_.y, bflo(v.w), ic); id = fmaf(w_.y, bfhi(v.w), id); }
    for (; j + 8 <= end; j += 8) {
        int s0 = src[j], s1 = src[j + 1], s2 = src[j + 2], s3 = src[j + 3];
        int s4 = src[j + 4], s5 = src[j + 5], s6 = src[j + 6], s7 = src[j + 7];
        float2 w0 = w[j], w1 = w[j + 1], w2 = w[j + 2], w3 = w[j + 3];
        float2 w4 = w[j + 4], w5 = w[j + 5], w6 = w[j + 6], w7 = w[j + 7];
        P2STEP(s0, w0); P2STEP(s1, w1); P2STEP(s2, w2); P2STEP(s3, w3);
        P2STEP(s4, w4); P2STEP(s5, w5); P2STEP(s6, w6); P2STEP(s7, w7);
    }
    for (; j + 4 <= end; j += 4) {
        int s0 = src[j], s1 = src[j + 1], s2 = src[j + 2], s3 = src[j + 3];
        float2 w0 = w[j], w1 = w[j + 1], w2 = w[j + 2], w3 = w[j + 3];
        P2STEP(s0, w0); P2STEP(s1, w1); P2STEP(s2, w2); P2STEP(s3, w3);
    }
    for (; j < end; ++j) {
        int s = src[j]; float2 wv = w[j];
        P2STEP(s, wv);
    }
#undef P2STEP
    uint2 ux = *(const uint2*)(Xc + (size_t)node * 128 + 4 * p);
    float xa = bflo(ux.x), xb = bfhi(ux.x), xc = bflo(ux.y), xd = bfhi(ux.y);
    uint4 o;
    o.x = packbf(2.f * oa - xa, 2.f * ob - xb);
    o.y = packbf(2.f * ia - xa, 2.f * ib - xb);
    o.z = packbf(2.f * oc - xc, 2.f * od - xd);
    o.w = packbf(2.f * ic - xc, 2.f * id - xd);
    int tile = node >> 4, lr = node & 15, ck = p >> 2, q = p & 3;
    *(uint4*)(P2p + (((size_t)tile * 8 + ck) * 64 + q * 16 + lr) * 8) = o;
}

__global__ void prop1_64(const unsigned short* __restrict__ HR,
                         const int* __restrict__ rowptr, const int* __restrict__ src,
                         const float2* __restrict__ w,
                         unsigned short* __restrict__ Q1, unsigned short* __restrict__ Q1p,
                         int n) {
    int tid = blockIdx.x * blockDim.x + threadIdx.x;
    int lane = tid & 63;
    int node = ((tid >> 6) << 2) + (lane >> 4);
    int p = lane & 15;
    if (node >= n) return;
    int beg = rowptr[node], end = rowptr[node + 1];
    float ao0 = 0.f, ao1 = 0.f, ao2 = 0.f, ao3 = 0.f;
    float ai0 = 0.f, ai1 = 0.f, ai2 = 0.f, ai3 = 0.f;
    int j = beg;
#define Q1STEP(s_, w_) {                                                     \
        uint2 u = *(const uint2*)(HR + (size_t)(s_) * 64 + 4 * p);           \
        float c0 = bflo(u.x), c1 = bfhi(u.x), c2 = bflo(u.y), c3 = bfhi(u.y);\
        ao0 = fmaf(w_.x, c0, ao0); ao1 = fmaf(w_.x, c1, ao1);                \
        ao2 = fmaf(w_.x, c2, ao2); ao3 = fmaf(w_.x, c3, ao3);                \
        ai0 = fmaf(w_.y, c0, ai0); ai1 = fmaf(w_.y, c1, ai1);                \
        ai2 = fmaf(w_.y, c2, ai2); ai3 = fmaf(w_.y, c3, ai3); }
    for (; j + 8 <= end; j += 8) {
        int s0 = src[j], s1 = src[j + 1], s2 = src[j + 2], s3 = src[j + 3];
        int s4 = src[j + 4], s5 = src[j + 5], s6 = src[j + 6], s7 = src[j + 7];
        float2 w0 = w[j], w1 = w[j + 1], w2 = w[j + 2], w3 = w[j + 3];
        float2 w4 = w[j + 4], w5 = w[j + 5], w6 = w[j + 6], w7 = w[j + 7];
        Q1STEP(s0, w0); Q1STEP(s1, w1); Q1STEP(s2, w2); Q1STEP(s3, w3);
        Q1STEP(s4, w4); Q1STEP(s5, w5); Q1STEP(s6, w6); Q1STEP(s7, w7);
    }
    for (; j + 4 <= end; j += 4) {
        int s0 = src[j], s1 = src[j + 1], s2 = src[j + 2], s3 = src[j + 3];
        float2 w0 = w[j], w1 = w[j + 1], w2 = w[j + 2], w3 = w[j + 3];
        Q1STEP(s0, w0); Q1STEP(s1, w1); Q1STEP(s2, w2); Q1STEP(s3, w3);
    }
    for (; j < end; ++j) {
        int s = src[j]; float2 wv = w[j];
        Q1STEP(s, wv);
    }
#undef Q1STEP
    uint4 o;
    o.x = packbf(ao0, ao1); o.y = packbf(ai0, ai1);
    o.z = packbf(ao2, ao3); o.w = packbf(ai2, ai3);
    *(uint4*)(Q1 + (size_t)node * 128 + 8 * p) = o;
    int tile = node >> 4, lr = node & 15, ck = p >> 2, q = p & 3;
    *(uint4*)(Q1p + (((size_t)tile * 4 + ck) * 64 + q * 16 + lr) * 8) = o;
}

__global__ void prop2_64(const unsigned short* __restrict__ Q1,
                         const unsigned short* __restrict__ HR,
                         const int* __restrict__ rowptr, const int* __restrict__ src,
                         const float2* __restrict__ w,
                         unsigned short* __restrict__ Q2p, int n) {
    int tid = blockIdx.x * blockDim.x + threadIdx.x;
    int lane = tid & 63;
    int node = ((tid >> 6) << 2) + (lane >> 4);
    int p = lane & 15;
    if (node >= n) return;
    int beg = rowptr[node], end = rowptr[node + 1];
    float oa = 0.f, ob = 0.f, oc = 0.f, od = 0.f;
    float ia = 0.f, ib = 0.f, ic = 0.f, id = 0.f;
    int j = beg;
#define Q2STEP(s_, w_) {                                                     \
        uint4 v = *(const uint4*)(Q1 + (size_t)(s_) * 128 + 8 * p);          \
        oa = fmaf(w_.x, bflo(v.x), oa); ob = fmaf(w_.x, bfhi(v.x), ob);      \
        ia = fmaf(w_.y, bflo(v.y), ia); ib = fmaf(w_.y, bfhi(v.y), ib);      \
        oc = fmaf(w_.x, bflo(v.z), oc); od = fmaf(w_.x, bfhi(v.z), od);      \
        ic = fmaf(w_.y, bflo(v.w), ic); id = fmaf(w_.y, bfhi(v.w), id); }
    for (; j + 8 <= end; j += 8) {
        int s0 = src[j], s1 = src[j + 1], s2 = src[j + 2], s3 = src[j + 3];
        int s4 = src[j + 4], s5 = src[j + 5], s6 = src[j + 6], s7 = src[j + 7];
        float2 w0 = w[j], w1 = w[j + 1], w2 = w[j + 2], w3 = w[j + 3];
        float2 w4 = w[j + 4], w5 = w[j + 5], w6 = w[j + 6], w7 = w[j + 7];
        Q2STEP(s0, w0); Q2STEP(s1, w1); Q2STEP(s2, w2); Q2STEP(s3, w3);
        Q2STEP(s4, w4); Q2STEP(s5, w5); Q2STEP(s6, w6); Q2STEP(s7, w7);
    }
    for (; j + 4 <= end; j += 4) {
        int s0 = src[j], s1 = src[j + 1], s2 = src[j + 2], s3 = src[j + 3];
        float2 w0 = w[j], w1 = w[j + 1], w2 = w[j + 2], w3 = w[j + 3];
        Q2STEP(s0, w0); Q2STEP(s1, w1); Q2STEP(s2, w2); Q2STEP(s3, w3);
    }
    for (; j < end; ++j) {
        int s = src[j]; float2 wv = w[j];
        Q2STEP(s, wv);
    }
#undef Q2STEP
    uint2 ux = *(const uint2*)(HR + (size_t)node * 64 + 4 * p);
    float xa = bflo(ux.x), xb = bfhi(ux.x), xc = bflo(ux.y), xd = bfhi(ux.y);
    uint4 o;
    o.x = packbf(2.f * oa - xa, 2.f * ob - xb);
    o.y = packbf(2.f * ia - xa, 2.f * ib - xb);
    o.z = packbf(2.f * oc - xc, 2.f * od - xd);
    o.w = packbf(2.f * ic - xc, 2.f * id - xd);
    int tile = node >> 4, lr = node & 15, ck = p >> 2, q = p & 3;
    *(uint4*)(Q2p + (((size_t)tile * 4 + ck) * 64 + q * 16 + lr) * 8) = o;
}

// ---------------- MFMA GEMMs: fragment-packed A and B, no LDS, no barriers --
// All frag loads are coalesced 1KB wave loads: lane i reads 16B at base+16i.
// mfma_f32_16x16x32_bf16 C/D: col=lane&15, row=(lane>>4)*4+reg.

// ZR: block 64 rows x 128 cols; 4 waves each 64 rows x 32 cols (ngrp = wid).
__global__ __launch_bounds__(256) void gemm_zr_mfma(
    const unsigned short* __restrict__ XHp, const unsigned short* __restrict__ P1p,
    const unsigned short* __restrict__ P2p,
    const unsigned short* __restrict__ Wf, const float* __restrict__ bz,
    const float* __restrict__ br, const float* __restrict__ H,
    float* __restrict__ Zf, unsigned short* __restrict__ HR, int n) {
    int tid = threadIdx.x;
    int lane = tid & 63;
    int ngrp = tid >> 6;
    int rowbase = blockIdx.x * 64;
    int lr = lane & 15, quad = lane >> 4;

    int tiles[4];
#pragma unroll
    for (int mt = 0; mt < 4; ++mt) {
        int t = (rowbase >> 4) + mt;
        tiles[mt] = (t > N_TILES - 1) ? N_TILES - 1 : t;
    }

    f32x4 zero = {0.f, 0.f, 0.f, 0.f};
    f32x4 acc[4][2];
#pragma unroll
    for (int a = 0; a < 4; ++a)
#pragma unroll
        for (int b = 0; b < 2; ++b) acc[a][b] = zero;

#pragma unroll
    for (int ks = 0; ks < 20; ++ks) {
        const unsigned short* T = (ks < 4) ? XHp : (ks < 12) ? P1p : P2p;
        int ck = (ks < 4) ? ks : (ks < 12) ? ks - 4 : ks - 12;
        int nck = (ks < 4) ? 4 : 8;
        bf8 b0 = *(const bf8*)(Wf + (((size_t)ks * 8 + ngrp * 2 + 0) * 64 + lane) * 8);
        bf8 b1 = *(const bf8*)(Wf + (((size_t)ks * 8 + ngrp * 2 + 1) * 64 + lane) * 8);
#pragma unroll
        for (int mt = 0; mt < 4; ++mt) {
            bf8 a = *(const bf8*)(T + (((size_t)tiles[mt] * nck + ck) * 64 + lane) * 8);
            acc[mt][0] = __builtin_amdgcn_mfma_f32_16x16x32_bf16(a, b0, acc[mt][0], 0, 0, 0);
            acc[mt][1] = __builtin_amdgcn_mfma_f32_16x16x32_bf16(a, b1, acc[mt][1], 0, 0, 0);
        }
    }
#pragma unroll
    for (int mt = 0; mt < 4; ++mt)
#pragma unroll
        for (int reg = 0; reg < 4; ++reg) {
            int r = rowbase + mt * 16 + quad * 4 + reg;
            if (r >= n) continue;
#pragma unroll
            for (int nt = 0; nt < 2; ++nt) {
                int cidx = ngrp * 32 + nt * 16 + lr;
                float bias = (cidx < 64) ? bz[cidx] : br[cidx - 64];
                float v = acc[mt][nt][reg] + bias;
                float s = 1.f / (1.f + expf(-v));
                if (cidx < 64) {
                    Zf[(size_t)r * 64 + cidx] = s;
                } else {
                    int c2 = cidx - 64;
                    HR[(size_t)r * 64 + c2] = f2bfu(H[(size_t)r * 64 + c2] * s);
                }
            }
        }
}

// H~: block 128 rows x 64 cols; 4 waves = (mh = wid&1 row-half, ngrp = wid>>1),
// each 64 rows x 32 cols. ks: 0-1 XHp, 2-5 P1p, 6-9 P2p(X-half), 10-11 HR
// (row-major strided, only 2/20), 12-15 Q1p, 16-19 Q2p.
__global__ __launch_bounds__(256) void gemm_h_mfma(
    const unsigned short* __restrict__ XHp, const unsigned short* __restrict__ P1p,
    const unsigned short* __restrict__ P2p, const unsigned short* __restrict__ HR,
    const unsigned short* __restrict__ Q1p, const unsigned short* __restrict__ Q2p,
    const unsigned short* __restrict__ Wf, const float* __restrict__ bh,
    const float* __restrict__ Zf, const float* __restrict__ H,
    float* __restrict__ out, int n) {
    int tid = threadIdx.x;
    int lane = tid & 63;
    int wid = tid >> 6;
    int mh = wid & 1, ngrp = wid >> 1;
    int rowbase = blockIdx.x * 128 + mh * 64;
    int lr = lane & 15, quad = lane >> 4;

    int tiles[4];
    const unsigned short* hrp[4];
#pragma unroll
    for (int mt = 0; mt < 4; ++mt) {
        int t = (rowbase >> 4) + mt;
        tiles[mt] = (t > N_TILES - 1) ? N_TILES - 1 : t;
        int r = rowbase + mt * 16 + lr;
        if (r >= n) r = n - 1;
        hrp[mt] = HR + (size_t)r * 64 + quad * 8;
    }

    f32x4 zero = {0.f, 0.f, 0.f, 0.f};
    f32x4 acc[4][2];
#pragma unroll
    for (int a = 0; a < 4; ++a)
#pragma unroll
        for (int b = 0; b < 2; ++b) acc[a][b] = zero;

#pragma unroll
    for (int ks = 0; ks < 20; ++ks) {
        bf8 b0 = *(const bf8*)(Wf + (((size_t)ks * 4 + ngrp * 2 + 0) * 64 + lane) * 8);
        bf8 b1 = *(const bf8*)(Wf + (((size_t)ks * 4 + ngrp * 2 + 1) * 64 + lane) * 8);
#pragma unroll
        for (int mt = 0; mt < 4; ++mt) {
            bf8 a;
            if (ks == 10 || ks == 11) {
                a = *(const bf8*)(hrp[mt] + (ks - 10) * 32);
            } else {
                const unsigned short* T = (ks < 2) ? XHp : (ks < 6) ? P1p :
                                          (ks < 10) ? P2p : (ks < 16) ? Q1p : Q2p;
                int ck = (ks < 2) ? ks : (ks < 6) ? ks - 2 : (ks < 10) ? ks - 6 :
                         (ks < 16) ? ks - 12 : ks - 16;
                int nck = (ks < 2) ? 4 : (ks < 10) ? 8 : 4;
                a = *(const bf8*)(T + (((size_t)tiles[mt] * nck + ck) * 64 + lane) * 8);
            }
            acc[mt][0] = __builtin_amdgcn_mfma_f32_16x16x32_bf16(a, b0, acc[mt][0], 0, 0, 0);
            acc[mt][1] = __builtin_amdgcn_mfma_f32_16x16x32_bf16(a, b1, acc[mt][1], 0, 0, 0);
        }
    }
#pragma unroll
    for (int mt = 0; mt < 4; ++mt)
#pragma unroll
        for (int reg = 0; reg < 4; ++reg) {
            int r = rowbase + mt * 16 + quad * 4 + reg;
            if (r >= n) continue;
#pragma unroll
            for (int nt = 0; nt < 2; ++nt) {
                int cidx = ngrp * 32 + nt * 16 + lr;
                float ht = tanhf(acc[mt][nt][reg] + bh[cidx]);
                float z = Zf[(size_t)r * 64 + cidx];
                float h_old = H[(size_t)r * 64 + cidx];
                out[(size_t)r * 64 + cidx] = z * h_old + (1.f - z) * ht;
            }
        }
}

// ---------------- launch ----------------

static inline size_t rup(size_t x) { return (x + 63) & ~(size_t)63; }

extern "C" void kernel_launch(void* const* d_in, const int* in_sizes, int n_in,
                              void* d_out, int out_size, void* d_ws, size_t ws_size,
                              hipStream_t stream) {
    const float* X  = (const float*)d_in[0];
    const int*   EI = (const int*)d_in[1];
    const float* H  = (const float*)d_in[2];
    const float* Wz = (const float*)d_in[3];
    const float* bz = (const float*)d_in[4];
    const float* Wr = (const float*)d_in[5];
    const float* br = (const float*)d_in[6];
    const float* Wh = (const float*)d_in[7];
    const float* bh = (const float*)d_in[8];
    float* out = (float*)d_out;

    const int* row = EI;
    const int* col = EI + N_EDGES;

    char* ws = (char*)d_ws;
    size_t off = 0;
    auto carve = [&](size_t bytes) { void* p = ws + off; off += rup(bytes); return p; };

    int*   deg_out   = (int*)carve(N_NODES * 4);
    int*   deg_in    = (int*)carve(N_NODES * 4);
    int*   rowptr    = (int*)carve((N_NODES + 1) * 4);
    int*   cursor    = (int*)carve(N_NODES * 4);
    int*   blocksums = (int*)carve(64 * 4);
    float2* winv     = (float2*)carve(N_NODES * 8);
    int*   csr_src   = (int*)carve(N_EDGES * 4);
    float2* csr_w    = (float2*)carve(N_EDGES * 8);
    unsigned short* XH  = (unsigned short*)carve((size_t)N_NODES * 128 * 2);  // dead after prop2_128
    unsigned short* P1  = (unsigned short*)carve((size_t)N_NODES * 256 * 2);  // dead after prop2_128
    unsigned short* XHp = (unsigned short*)carve((size_t)N_TILES * 4 * 512 * 2);
    unsigned short* P1p = (unsigned short*)carve((size_t)N_TILES * 8 * 512 * 2);
    unsigned short* P2p = (unsigned short*)carve((size_t)N_TILES * 8 * 512 * 2);
    unsigned short* HR  = (unsigned short*)carve((size_t)N_NODES * 64 * 2);
    float* Zf           = (float*)carve((size_t)N_NODES * 64 * 4);
    unsigned short* Wzrf = (unsigned short*)carve(20 * 8 * 64 * 8 * 2);
    unsigned short* Whf  = (unsigned short*)carve(20 * 4 * 64 * 8 * 2);

    // Aliases (regions dead by the time these are written):
    unsigned short* Q1  = XH;                                  // [n][128] row-major
    unsigned short* Q1p = P1;                                  // fragment-packed, 12.8 MB
    unsigned short* Q2p = P1 + (size_t)N_TILES * 4 * 512;      // fragment-packed, 12.8 MB

    hipMemsetAsync(deg_out, 0, rup(N_NODES * 4) + rup(N_NODES * 4), stream);
    count_deg<<<(N_EDGES + 255) / 256, 256, 0, stream>>>(row, col, deg_out, deg_in, N_EDGES);

    int nblk = (N_NODES + 1023) / 1024;
    scan_block<<<nblk, 1024, 0, stream>>>(deg_in, rowptr, blocksums, N_NODES);
    scan_sums<<<1, 64, 0, stream>>>(blocksums, nblk);
    scan_add<<<(N_NODES + 1 + 255) / 256, 256, 0, stream>>>(rowptr, blocksums, cursor,
                                                            deg_out, deg_in, winv, N_NODES, N_EDGES);

    // fused: build_csr + concat_xh + pack_weights
    fused_prep<<<CSR_BLOCKS + CONCAT_BLOCKS + PACK_BLOCKS, 256, 0, stream>>>(
        row, col, winv, cursor, csr_src, csr_w,
        X, H, XH, XHp, Wz, Wr, Wh, Wzrf, Whf, N_NODES, N_EDGES);

    // props on XH: 2 nodes/wave
    int blocks_p128 = (((N_NODES + 1) / 2) * 64 + 255) / 256;
    prop1_128<<<blocks_p128, 256, 0, stream>>>(XH, rowptr, csr_src, csr_w, P1, P1p, N_NODES);
    prop2_128<<<blocks_p128, 256, 0, stream>>>(P1, XH, rowptr, csr_src, csr_w, P2p, N_NODES);

    // Z|R GEMM -> Zf, HR   (XH, P1 row-major now dead)
    int zr_blocks = (N_NODES + 63) / 64;
    gemm_zr_mfma<<<zr_blocks, 256, 0, stream>>>(XHp, P1p, P2p, Wzrf, bz, br, H, Zf, HR, N_NODES);

    // props on HR: 4 nodes/wave
    int blocks_p64 = (((N_NODES + 3) / 4) * 64 + 255) / 256;
    prop1_64<<<blocks_p64, 256, 0, stream>>>(HR, rowptr, csr_src, csr_w, Q1, Q1p, N_NODES);
    prop2_64<<<blocks_p64, 256, 0, stream>>>(Q1, HR, rowptr, csr_src, csr_w, Q2p, N_NODES);

    // H~ GEMM + GRU mix -> out
    int h_blocks = (N_NODES + 127) / 128;
    gemm_h_mfma<<<h_blocks, 256, 0, stream>>>(XHp, P1p, P2p, HR, Q1p, Q2p,
                                              Whf, bh, Zf, H, out, N_NODES);
}